// Round 7
// baseline (282.442 us; speedup 1.0000x reference)
//
#include <hip/hip_runtime.h>
#include <stdint.h>

#define T_LEN 1024
#define NSTATE 32

typedef int v2i __attribute__((ext_vector_type(2)));

__device__ __forceinline__ float max3f(float a, float b, float c) {
    return fmaxf(fmaxf(a, b), c);   // v_max3_f32
}
__device__ __forceinline__ int min3i(int a, int b, int c) {
    return min(min(a, b), c);       // v_min3_i32
}

// DPP row-rotate by n within each 16-lane row (pure VALU, no LDS pipe)
#define ROR(x, n) __builtin_amdgcn_mov_dpp((x), 0x120 + (n), 0xF, 0xF, false)

// All-gather the 16 values of this lane's 16-row into g[0..15].
// g[k] = value rotated by k (direction is hardware-defined but CONSISTENT;
// the pidx probe below flows through this same network, so any direction works).
__device__ __forceinline__ void gather16(int x, int g[16]) {
    g[0]  = x;
    g[1]  = ROR(g[0], 1);
    g[2]  = ROR(g[0], 2);
    g[3]  = ROR(g[1], 2);
    g[4]  = ROR(g[0], 4);
    g[5]  = ROR(g[1], 4);
    g[6]  = ROR(g[2], 4);
    g[7]  = ROR(g[3], 4);
    g[8]  = ROR(g[0], 8);
    g[9]  = ROR(g[1], 8);
    g[10] = ROR(g[2], 8);
    g[11] = ROR(g[3], 8);
    g[12] = ROR(g[4], 8);
    g[13] = ROR(g[5], 8);
    g[14] = ROR(g[6], 8);
    g[15] = ROR(g[7], 8);
}

// Exchange with lane^16 (row swap). Returns partner's value. Robust to either
// operand-pairing convention: both inputs hold `own`, so any cross-row datum
// equals the partner's value; bitwise compare picks whichever reg crossed.
__device__ __forceinline__ int xrow16_partner(int own) {
    int a = own, b = own;
#if __has_builtin(__builtin_amdgcn_permlane16_swap)
    v2i r = __builtin_amdgcn_permlane16_swap(a, b, false, false);
    a = r[0]; b = r[1];
#else
    asm volatile("v_permlane16_swap_b32 %0, %1" : "+v"(a), "+v"(b));
#endif
    return (a == own) ? b : a;
}

__launch_bounds__(64)
__global__ void viterbi_kernel(const float* __restrict__ logits,
                               const float* __restrict__ trans,
                               const int* __restrict__ seqlen,
                               int* __restrict__ out)
{
    const int lane = threadIdx.x;   // 0..63
    const int j    = lane & 31;     // output column owned by this lane
    // state layout: lane l holds s[myidx]; rows hold contiguous halves so the
    // two 32-halves cover complementary candidate halves for the same j.
    const int myidx = (lane < 32) ? j : (j ^ 16);
    const bool upper = lane >= 32;

    __shared__ uint8_t bp[T_LEN * NSTATE];      // backptrs, t=1..L-1
    __shared__ uint8_t Farr[NSTATE * NSTATE];   // chunk functions
    __shared__ uint8_t earr[NSTATE];            // chunk entry tags
    __shared__ __align__(16) int pred[T_LEN];   // output row

    int L = seqlen[blockIdx.x];
    L = min(max(L, 0), T_LEN);

    // probe: push myidx through the gather network -> pidx[k] = source state
    // index held in register k after the same rotations. Direction-proof.
    int pidx[16];
    gather16(myidx, pidx);

    // pre-rotated transition column j matching the gathered layout
    float tr_rot[16];
#pragma unroll
    for (int k = 0; k < 16; ++k)
        tr_rot[k] = trans[pidx[k] * NSTATE + j];

    const float* lg = logits + (size_t)blockIdx.x * T_LEN * NSTATE;

    // init: lane holds state[myidx] = logits[b,0,myidx]
    float ns = lg[myidx];

    // one forward step (pure-VALU chain; only DS op is the bp byte write)
    auto step = [&](int t, float lgt) {
        int gb[16];
        gather16(__float_as_int(ns), gb);    // 15 v_mov_dpp

        float v[16];
#pragma unroll
        for (int k = 0; k < 16; ++k)
            v[k] = __int_as_float(gb[k]) + tr_rot[k];

        // max over this half's 16 candidates (max3 tree, exact)
        float a0 = max3f(v[0],  v[1],  v[2]);
        float a1 = max3f(v[3],  v[4],  v[5]);
        float a2 = max3f(v[6],  v[7],  v[8]);
        float a3 = max3f(v[9],  v[10], v[11]);
        float a4 = max3f(v[12], v[13], v[14]);
        float b0 = max3f(a0, a1, a2);
        float b1 = max3f(a3, a4, v[15]);
        float hm = fmaxf(b0, b1);

        // cross-half combine (lane^32 holds the other 16 candidates), VALU pipe
        v2i sw = __builtin_amdgcn_permlane32_swap(__float_as_int(hm),
                                                  __float_as_int(hm), false, false);
        float gm = fmaxf(hm, fmaxf(__int_as_float(sw[0]), __int_as_float(sw[1])));

        ns = gm + lgt;    // same single-rounding add order as reference

        // argmax with exact first-occurrence tie-break (min true source index)
        int ix[16];
#pragma unroll
        for (int k = 0; k < 16; ++k)
            ix[k] = (v[k] == gm) ? pidx[k] : 64;
        int c0 = min3i(ix[0],  ix[1],  ix[2]);
        int c1 = min3i(ix[3],  ix[4],  ix[5]);
        int c2 = min3i(ix[6],  ix[7],  ix[8]);
        int c3 = min3i(ix[9],  ix[10], ix[11]);
        int c4 = min3i(ix[12], ix[13], ix[14]);
        int d0 = min3i(c0, c1, c2);
        int d1 = min3i(c3, c4, ix[15]);
        int ih = min(d0, d1);
        v2i swi = __builtin_amdgcn_permlane32_swap(ih, ih, false, false);
        int idx = min(ih, min(swi[0], swi[1]));

        bp[t * NSTATE + j] = (uint8_t)idx;   // dup same-value byte write, benign

        // relayout for next step: upper lanes need ns' of column j^16,
        // which lives at lane^16 (both rows just computed their own j).
        int part = xrow16_partner(__float_as_int(ns));
        if (upper) ns = __int_as_float(part);
    };

    // ---------------- forward (single wave: no barriers) ----------------
    // NOTE: all pre[] indices are compile-time constants (no runtime-indexed
    // tail!) so pre[] stays in VGPRs — a runtime-indexed access would demote
    // the array to scratch and put a ~450cy scratch_load on the serial chain.
    if (L >= 2) {
        float pre[8];
#pragma unroll
        for (int d = 0; d < 8; ++d) {
            int tp = 1 + d; if (tp > 1023) tp = 1023;
            pre[d] = lg[tp * NSTATE + j];
        }
        for (int t = 1; t < L; t += 8) {
#pragma unroll
            for (int u = 0; u < 8; ++u) {
                if (t + u < L)                  // wave-uniform scalar branch
                    step(t + u, pre[u]);
                int tp = t + 8 + u; if (tp > 1023) tp = 1023;
                pre[u] = lg[tp * NSTATE + j];
            }
        }
    }

    // ---------------- last_tag = argmax(final state) ----------------
    // every state value appears exactly twice across the 64 lanes (at myidx)
    float m = ns;
#pragma unroll
    for (int d = 1; d < 64; d <<= 1) m = fmaxf(m, __shfl_xor(m, d));
    int ii = (ns == m) ? myidx : 64;
#pragma unroll
    for (int d = 1; d < 64; d <<= 1) ii = min(ii, __shfl_xor(ii, d));
    const int ft = ii;   // last tag (identical in all lanes)

    __syncthreads();   // bp visible for backtrace

    // ---- phase 1: chunk functions, all 32 start states (halves split k) ----
    {
        const int c = lane & 31;
        const int j0base = (lane >> 5) * 16;
        int tags[16];
#pragma unroll
        for (int k = 0; k < 16; ++k) tags[k] = j0base + k;
        const int thi = c * 32 + 31;
        for (int s = 0; s < 32; ++s) {
            int t = thi - s;
            bool valid = (t >= 1) && (t <= L - 1);
            int tc = min(max(t, 1), max(L - 1, 1));
            int base = tc * NSTATE;
#pragma unroll
            for (int k = 0; k < 16; ++k) {
                int nt = bp[base + tags[k]];
                tags[k] = valid ? nt : tags[k];
            }
        }
#pragma unroll
        for (int k = 0; k < 16; ++k)
            Farr[c * 32 + j0base + k] = (uint8_t)tags[k];
    }
    __syncthreads();

    // ---- phase 2: compose chunk entries (serial, 32 steps) ----
    if (lane == 0) {
        int e = ft;
        for (int c2 = 31; c2 >= 0; --c2) {
            earr[c2] = (uint8_t)e;
            e = Farr[c2 * 32 + e];
        }
    }
    __syncthreads();

    // ---- phase 3: re-walk chunks in parallel, emit pred (predication
    //      handles L<2: pred[t]=0 for t>=L, pred[0]=ft when L==1) ----
    if (lane < 32) {
        int tag = earr[lane];
        const int thi3 = lane * 32 + 31;
        for (int s = 0; s < 32; ++s) {
            int t = thi3 - s;
            pred[t] = (t < L) ? tag : 0;
            bool valid = (t >= 1) && (t <= L - 1);
            int tc = min(max(t, 1), max(L - 1, 1));
            int nt = bp[tc * NSTATE + tag];
            tag = valid ? nt : tag;
        }
    }
    __syncthreads();

    // ---------------- coalesced store ----------------
    int4* out4 = reinterpret_cast<int4*>(out + (size_t)blockIdx.x * T_LEN);
    const int4* p4 = reinterpret_cast<const int4*>(pred);
#pragma unroll
    for (int r = 0; r < 4; ++r)
        out4[r * 64 + lane] = p4[r * 64 + lane];
}

extern "C" void kernel_launch(void* const* d_in, const int* in_sizes, int n_in,
                              void* d_out, int out_size, void* d_ws, size_t ws_size,
                              hipStream_t stream) {
    const float* logits = (const float*)d_in[0];
    const float* trans  = (const float*)d_in[1];
    const int*   slen   = (const int*)d_in[2];
    int*         out    = (int*)d_out;
    const int B = in_sizes[2];   // 1024

    viterbi_kernel<<<dim3(B), dim3(64), 0, stream>>>(logits, trans, slen, out);
}

// Round 8
// 261.678 us; speedup vs baseline: 1.0794x; 1.0794x over previous
//
#include <hip/hip_runtime.h>
#include <stdint.h>

#define T_LEN 1024
#define NSTATE 32

typedef int v2i __attribute__((ext_vector_type(2)));

__device__ __forceinline__ float max3f(float a, float b, float c) {
    return fmaxf(fmaxf(a, b), c);   // v_max3_f32
}
__device__ __forceinline__ int min3i(int a, int b, int c) {
    return min(min(a, b), c);       // v_min3_i32
}

// DPP row-rotate by n within each 16-lane row (pure VALU, no LDS pipe)
#define ROR(x, n) __builtin_amdgcn_mov_dpp((x), 0x120 + (n), 0xF, 0xF, false)

// All-gather the 16 values of this lane's 16-row into g[0..15].
__device__ __forceinline__ void gather16(int x, int g[16]) {
    g[0]  = x;
    g[1]  = ROR(g[0], 1);
    g[2]  = ROR(g[0], 2);
    g[3]  = ROR(g[1], 2);
    g[4]  = ROR(g[0], 4);
    g[5]  = ROR(g[1], 4);
    g[6]  = ROR(g[2], 4);
    g[7]  = ROR(g[3], 4);
    g[8]  = ROR(g[0], 8);
    g[9]  = ROR(g[1], 8);
    g[10] = ROR(g[2], 8);
    g[11] = ROR(g[3], 8);
    g[12] = ROR(g[4], 8);
    g[13] = ROR(g[5], 8);
    g[14] = ROR(g[6], 8);
    g[15] = ROR(g[7], 8);
}

// Exchange with lane^16 (row swap). Returns partner's value (convention-proof).
__device__ __forceinline__ int xrow16_partner(int own) {
    int a = own, b = own;
#if __has_builtin(__builtin_amdgcn_permlane16_swap)
    v2i r = __builtin_amdgcn_permlane16_swap(a, b, false, false);
    a = r[0]; b = r[1];
#else
    asm volatile("v_permlane16_swap_b32 %0, %1" : "+v"(a), "+v"(b));
#endif
    return (a == own) ? b : a;
}

// s_waitcnt vmcnt(8), lgkmcnt/expcnt unconstrained: imm = 0xF00|0x70|8
#define WAIT_VM8() do { __builtin_amdgcn_s_waitcnt(0xF78); \
                        __builtin_amdgcn_sched_barrier(0); } while (0)

__launch_bounds__(64)
__global__ void viterbi_kernel(const float* __restrict__ logits,
                               const float* __restrict__ trans,
                               const int* __restrict__ seqlen,
                               int* __restrict__ out)
{
    const int lane = threadIdx.x;   // 0..63
    const int j    = lane & 31;     // output column owned by this lane
    const int myidx = (lane < 32) ? j : (j ^ 16);
    const bool upper = lane >= 32;

    __shared__ uint8_t bp[(T_LEN + 1) * NSTATE];  // backptrs (+1 padded row)
    __shared__ uint8_t Farr[NSTATE * NSTATE];     // chunk functions
    __shared__ uint8_t earr[NSTATE];              // chunk entry tags
    __shared__ __align__(16) int pred[T_LEN];     // output row

    int L = seqlen[blockIdx.x];
    L = min(max(L, 0), T_LEN);

    // probe: pidx[k] = true source-state index in gathered register k
    int pidx[16];
    gather16(myidx, pidx);

    float tr_rot[16];
#pragma unroll
    for (int k = 0; k < 16; ++k)
        tr_rot[k] = trans[pidx[k] * NSTATE + j];

    const float* lg = logits + (size_t)blockIdx.x * T_LEN * NSTATE;

    float ns = lg[myidx];   // lane holds state[myidx]

    // one forward step; fully branchless (act is wave-uniform)
    auto step = [&](int t, float lgt, bool act) {
        int gb[16];
        gather16(__float_as_int(ns), gb);    // 15 v_mov_dpp

        float v[16];
#pragma unroll
        for (int k = 0; k < 16; ++k)
            v[k] = __int_as_float(gb[k]) + tr_rot[k];

        float a0 = max3f(v[0],  v[1],  v[2]);
        float a1 = max3f(v[3],  v[4],  v[5]);
        float a2 = max3f(v[6],  v[7],  v[8]);
        float a3 = max3f(v[9],  v[10], v[11]);
        float a4 = max3f(v[12], v[13], v[14]);
        float b0 = max3f(a0, a1, a2);
        float b1 = max3f(a3, a4, v[15]);
        float hm = fmaxf(b0, b1);

        v2i sw = __builtin_amdgcn_permlane32_swap(__float_as_int(hm),
                                                  __float_as_int(hm), false, false);
        float gm = fmaxf(hm, fmaxf(__int_as_float(sw[0]), __int_as_float(sw[1])));

        float nsn = gm + lgt;          // same single-rounding add order as ref
        float ns_sel = act ? nsn : ns; // uniform select (no branch)

        // exact first-occurrence argmax (off the value chain)
        int ix[16];
#pragma unroll
        for (int k = 0; k < 16; ++k)
            ix[k] = (v[k] == gm) ? pidx[k] : 64;
        int c0 = min3i(ix[0],  ix[1],  ix[2]);
        int c1 = min3i(ix[3],  ix[4],  ix[5]);
        int c2 = min3i(ix[6],  ix[7],  ix[8]);
        int c3 = min3i(ix[9],  ix[10], ix[11]);
        int c4 = min3i(ix[12], ix[13], ix[14]);
        int d0 = min3i(c0, c1, c2);
        int d1 = min3i(c3, c4, ix[15]);
        int ih = min(d0, d1);
        v2i swi = __builtin_amdgcn_permlane32_swap(ih, ih, false, false);
        int idx = min3i(ih, swi[0], swi[1]);

        int tc = min(t, T_LEN);                 // rows >= L never read back
        bp[tc * NSTATE + j] = (uint8_t)idx;     // fire-and-forget DS byte

        // relayout for next step (only when the step was active)
        int part = xrow16_partner(__float_as_int(ns_sel));
        ns = (upper && act) ? __int_as_float(part) : ns_sel;
    };

    // ---------------- forward: 16-step groups, batched prefetch ----------------
    // All 8 loads of a group are issued together, consumed a full group (16
    // steps) later behind an explicit vmcnt(8) — loads are never fresh when
    // drained, and the 8 steps inside a group run with no memory waits.
    {
        const int steps = max(L - 1, 0);
        const int P = (steps + 15) & ~15;    // padded step count (×16)

        float preA[8], preB[8];
#pragma unroll
        for (int u = 0; u < 8; ++u) {
            int tp = min(1 + u, T_LEN - 1);
            preA[u] = lg[tp * NSTATE + j];
        }
#pragma unroll
        for (int u = 0; u < 8; ++u) {
            int tp = min(9 + u, T_LEN - 1);
            preB[u] = lg[tp * NSTATE + j];
        }

        for (int t = 1; t + 15 <= P; t += 16) {
            WAIT_VM8();                       // preA complete (preB in flight)
#pragma unroll
            for (int u = 0; u < 8; ++u)
                step(t + u, preA[u], (t + u) < L);
#pragma unroll
            for (int u = 0; u < 8; ++u) {     // batch-issue next A group
                int tp = min(t + 16 + u, T_LEN - 1);
                preA[u] = lg[tp * NSTATE + j];
            }
            WAIT_VM8();                       // preB complete (preA' in flight)
#pragma unroll
            for (int u = 0; u < 8; ++u)
                step(t + 8 + u, preB[u], (t + 8 + u) < L);
#pragma unroll
            for (int u = 0; u < 8; ++u) {     // batch-issue next B group
                int tp = min(t + 24 + u, T_LEN - 1);
                preB[u] = lg[tp * NSTATE + j];
            }
        }
    }

    // ---------------- last_tag = argmax(final state) ----------------
    float m = ns;
#pragma unroll
    for (int d = 1; d < 64; d <<= 1) m = fmaxf(m, __shfl_xor(m, d));
    int ii = (ns == m) ? myidx : 64;
#pragma unroll
    for (int d = 1; d < 64; d <<= 1) ii = min(ii, __shfl_xor(ii, d));
    const int ft = ii;   // last tag (identical in all lanes)

    __syncthreads();   // bp visible for backtrace

    // ---- phase 1: chunk functions, all 32 start states (halves split k) ----
    {
        const int c = lane & 31;
        const int j0base = (lane >> 5) * 16;
        int tags[16];
#pragma unroll
        for (int k = 0; k < 16; ++k) tags[k] = j0base + k;
        const int thi = c * 32 + 31;
        for (int s = 0; s < 32; ++s) {
            int t = thi - s;
            bool valid = (t >= 1) && (t <= L - 1);
            int tc = min(max(t, 1), max(L - 1, 1));
            int base = tc * NSTATE;
#pragma unroll
            for (int k = 0; k < 16; ++k) {
                int nt = bp[base + tags[k]];
                tags[k] = valid ? nt : tags[k];
            }
        }
#pragma unroll
        for (int k = 0; k < 16; ++k)
            Farr[c * 32 + j0base + k] = (uint8_t)tags[k];
    }
    __syncthreads();

    // ---- phase 2: compose chunk entries (serial, 32 steps) ----
    if (lane == 0) {
        int e = ft;
        for (int c2 = 31; c2 >= 0; --c2) {
            earr[c2] = (uint8_t)e;
            e = Farr[c2 * 32 + e];
        }
    }
    __syncthreads();

    // ---- phase 3: re-walk chunks in parallel, emit pred ----
    if (lane < 32) {
        int tag = earr[lane];
        const int thi3 = lane * 32 + 31;
        for (int s = 0; s < 32; ++s) {
            int t = thi3 - s;
            pred[t] = (t < L) ? tag : 0;
            bool valid = (t >= 1) && (t <= L - 1);
            int tc = min(max(t, 1), max(L - 1, 1));
            int nt = bp[tc * NSTATE + tag];
            tag = valid ? nt : tag;
        }
    }
    __syncthreads();

    // ---------------- coalesced store ----------------
    int4* out4 = reinterpret_cast<int4*>(out + (size_t)blockIdx.x * T_LEN);
    const int4* p4 = reinterpret_cast<const int4*>(pred);
#pragma unroll
    for (int r = 0; r < 4; ++r)
        out4[r * 64 + lane] = p4[r * 64 + lane];
}

extern "C" void kernel_launch(void* const* d_in, const int* in_sizes, int n_in,
                              void* d_out, int out_size, void* d_ws, size_t ws_size,
                              hipStream_t stream) {
    const float* logits = (const float*)d_in[0];
    const float* trans  = (const float*)d_in[1];
    const int*   slen   = (const int*)d_in[2];
    int*         out    = (int*)d_out;
    const int B = in_sizes[2];   // 1024

    viterbi_kernel<<<dim3(B), dim3(64), 0, stream>>>(logits, trans, slen, out);
}

// Round 9
// 250.733 us; speedup vs baseline: 1.1265x; 1.0437x over previous
//
#include <hip/hip_runtime.h>
#include <stdint.h>

#define T_LEN 1024
#define NSTATE 32

typedef int v2i __attribute__((ext_vector_type(2)));

__device__ __forceinline__ float max3f(float a, float b, float c) {
    return fmaxf(fmaxf(a, b), c);   // v_max3_f32
}
__device__ __forceinline__ int min3i(int a, int b, int c) {
    return min(min(a, b), c);       // v_min3_i32
}

__launch_bounds__(64)
__global__ void viterbi_kernel(const float* __restrict__ logits,
                               const float* __restrict__ trans,
                               const int* __restrict__ seqlen,
                               int* __restrict__ out)
{
    const int lane = threadIdx.x;   // 0..63
    const int half = lane >> 5;     // candidate half this lane reduces
    const int j    = lane & 31;     // output column (lanes j, j+32 duplicate)
    const int h16  = half * 16;

    __shared__ __align__(16) float st[NSTATE];   // state vector (broadcast row)
    __shared__ uint8_t bp[T_LEN * NSTATE];       // backptrs, t=1..L-1
    __shared__ uint8_t Farr[NSTATE * NSTATE];    // chunk functions
    __shared__ uint8_t earr[NSTATE];             // chunk entry tags
    __shared__ __align__(16) int pred[T_LEN];    // output row

    int L = seqlen[blockIdx.x];
    L = min(max(L, 0), T_LEN);

    // transition column j, rows h16..h16+15 (registers, loaded once)
    float tr[16];
#pragma unroll
    for (int k = 0; k < 16; ++k)
        tr[k] = trans[(h16 + k) * NSTATE + j];

    const float* lg = logits + (size_t)blockIdx.x * T_LEN * NSTATE;

    // running value of column j (dup in lanes j, j+32)
    float ns = lg[j];

    // init state row + issue first broadcast reads (constant addresses)
    st[j] = ns;                        // dup same-value write, benign
    const float4* stv = reinterpret_cast<const float4*>(st) + half * 4;
    float4 q0 = stv[0], q1 = stv[1], q2 = stv[2], q3 = stv[3];

    // one forward step. Entering: q* = S_{t-1}[h16..h16+15].
    // Order: adds -> max -> ns -> ds_write(st) -> ds_read(next q) -> argmax -> bp.
    // The read latency hides under the ~41-instr argmax block.
    auto step = [&](int t, float lgt) {
        float v[16];
        v[0]=q0.x+tr[0];  v[1]=q0.y+tr[1];  v[2]=q0.z+tr[2];  v[3]=q0.w+tr[3];
        v[4]=q1.x+tr[4];  v[5]=q1.y+tr[5];  v[6]=q1.z+tr[6];  v[7]=q1.w+tr[7];
        v[8]=q2.x+tr[8];  v[9]=q2.y+tr[9];  v[10]=q2.z+tr[10];v[11]=q2.w+tr[11];
        v[12]=q3.x+tr[12];v[13]=q3.y+tr[13];v[14]=q3.z+tr[14];v[15]=q3.w+tr[15];

        // half-max via max3 tree (exact, order-independent)
        float a0 = max3f(v[0],  v[1],  v[2]);
        float a1 = max3f(v[3],  v[4],  v[5]);
        float a2 = max3f(v[6],  v[7],  v[8]);
        float a3 = max3f(v[9],  v[10], v[11]);
        float a4 = max3f(v[12], v[13], v[14]);
        float b0 = max3f(a0, a1, a2);
        float b1 = max3f(a3, a4, v[15]);
        float hm = fmaxf(b0, b1);

        // cross-half combine on the VALU pipe (lane^32 has the other 16)
        v2i sw = __builtin_amdgcn_permlane32_swap(__float_as_int(hm),
                                                  __float_as_int(hm), false, false);
        float gm = fmaxf(hm, fmaxf(__int_as_float(sw[0]), __int_as_float(sw[1])));

        ns = gm + lgt;                 // same single-rounding add order as ref

        // publish S_t and immediately issue next-step broadcast reads;
        // their latency is covered by the argmax block below.
        st[j] = ns;
        q0 = stv[0]; q1 = stv[1]; q2 = stv[2]; q3 = stv[3];

        // exact first-occurrence argmax (off the value chain)
        int ix[16];
#pragma unroll
        for (int k = 0; k < 16; ++k)
            ix[k] = (v[k] == gm) ? (h16 + k) : 64;
        int c0 = min3i(ix[0],  ix[1],  ix[2]);
        int c1 = min3i(ix[3],  ix[4],  ix[5]);
        int c2 = min3i(ix[6],  ix[7],  ix[8]);
        int c3 = min3i(ix[9],  ix[10], ix[11]);
        int c4 = min3i(ix[12], ix[13], ix[14]);
        int d0 = min3i(c0, c1, c2);
        int d1 = min3i(c3, c4, ix[15]);
        int ih = min(d0, d1);
        v2i swi = __builtin_amdgcn_permlane32_swap(ih, ih, false, false);
        int idx = min3i(ih, swi[0], swi[1]);

        bp[t * NSTATE + j] = (uint8_t)idx;   // dup same-value byte write
    };

    // ---------------- forward (single wave: no barriers) ----------------
    if (L >= 2) {
        float pre[8];
#pragma unroll
        for (int d = 0; d < 8; ++d) {
            int tp = 1 + d; if (tp > 1023) tp = 1023;
            pre[d] = lg[tp * NSTATE + j];
        }
        int t = 1;
        for (; t + 8 <= L; t += 8) {
#pragma unroll
            for (int u = 0; u < 8; ++u) {
                step(t + u, pre[u]);
                int tp = t + 8 + u; if (tp > 1023) tp = 1023;
                pre[u] = lg[tp * NSTATE + j];
            }
        }
        for (int k = 0; t < L; ++t, ++k) step(t, pre[k]);
    }

    // ---------------- last_tag = argmax(final state) ----------------
    // lanes j and j+32 hold the same column value; reduce over all 64
    float m = ns;
#pragma unroll
    for (int d = 1; d < 64; d <<= 1) m = fmaxf(m, __shfl_xor(m, d));
    int ii = (ns == m) ? j : 64;
#pragma unroll
    for (int d = 1; d < 64; d <<= 1) ii = min(ii, __shfl_xor(ii, d));
    const int ft = ii;   // last tag (identical in all lanes)

    __syncthreads();   // bp visible for backtrace

    // ---- phase 1: chunk functions, all 32 start states (halves split k) ----
    {
        const int c = lane & 31;
        const int j0base = (lane >> 5) * 16;
        int tags[16];
#pragma unroll
        for (int k = 0; k < 16; ++k) tags[k] = j0base + k;
        const int thi = c * 32 + 31;
        for (int s = 0; s < 32; ++s) {
            int t = thi - s;
            bool valid = (t >= 1) && (t <= L - 1);
            int tc = min(max(t, 1), max(L - 1, 1));
            int base = tc * NSTATE;
#pragma unroll
            for (int k = 0; k < 16; ++k) {
                int nt = bp[base + tags[k]];
                tags[k] = valid ? nt : tags[k];
            }
        }
#pragma unroll
        for (int k = 0; k < 16; ++k)
            Farr[c * 32 + j0base + k] = (uint8_t)tags[k];
    }
    __syncthreads();

    // ---- phase 2: compose chunk entries (serial, 32 steps) ----
    if (lane == 0) {
        int e = ft;
        for (int c2 = 31; c2 >= 0; --c2) {
            earr[c2] = (uint8_t)e;
            e = Farr[c2 * 32 + e];
        }
    }
    __syncthreads();

    // ---- phase 3: re-walk chunks in parallel, emit pred (predication
    //      handles L<2: pred[t]=0 for t>=L, pred[0]=ft when L==1) ----
    if (lane < 32) {
        int tag = earr[lane];
        const int thi3 = lane * 32 + 31;
        for (int s = 0; s < 32; ++s) {
            int t = thi3 - s;
            pred[t] = (t < L) ? tag : 0;
            bool valid = (t >= 1) && (t <= L - 1);
            int tc = min(max(t, 1), max(L - 1, 1));
            int nt = bp[tc * NSTATE + tag];
            tag = valid ? nt : tag;
        }
    }
    __syncthreads();

    // ---------------- coalesced store ----------------
    int4* out4 = reinterpret_cast<int4*>(out + (size_t)blockIdx.x * T_LEN);
    const int4* p4 = reinterpret_cast<const int4*>(pred);
#pragma unroll
    for (int r = 0; r < 4; ++r)
        out4[r * 64 + lane] = p4[r * 64 + lane];
}

extern "C" void kernel_launch(void* const* d_in, const int* in_sizes, int n_in,
                              void* d_out, int out_size, void* d_ws, size_t ws_size,
                              hipStream_t stream) {
    const float* logits = (const float*)d_in[0];
    const float* trans  = (const float*)d_in[1];
    const int*   slen   = (const int*)d_in[2];
    int*         out    = (int*)d_out;
    const int B = in_sizes[2];   // 1024

    viterbi_kernel<<<dim3(B), dim3(64), 0, stream>>>(logits, trans, slen, out);
}